// Round 4
// baseline (245.790 us; speedup 1.0000x reference)
//
#include <hip/hip_runtime.h>

// Problem constants (fixed by the reference's setup_inputs)
#define NPEND  128
#define LATENT 256
#define KCOLS  6
#define D0_C   1.0f
#define NB_MAX 1024

typedef float f32x4 __attribute__((ext_vector_type(4)));

// Intermediate r rows (x,y,z,pad). 2 MB static device buffer — avoids any
// dependence on ws_size and any hip* allocation calls (graph-capture safe).
static __device__ float4 g_r[(size_t)NB_MAX * NPEND];

// ---------------------------------------------------------------------------
// Kernel 1 (read-bound): r[row] = y[row,:] @ K[:,0:3].
// Pure read stream: no __syncthreads, no LDS staging, writes only 2 MB.
// Wave layout: 4 rows per wave-iteration. lane = (g = lane>>4, sl = lane&15);
// lane loads y[row][sl*16 .. sl*16+15] (4x float4, 64B contiguous per lane,
// each 16-lane group covers a full 1KB row -> fully coalesced).
// Reduction: 4-round __shfl_xor within 16-lane groups = 3 DS ops/row.
// VGPR ~80 -> 16 waves/CU; in-flight ~48KB/CU >> 9.2KB needed for 6.3TB/s.
// ---------------------------------------------------------------------------
__global__ __launch_bounds__(256, 4)
void pend_r_kernel(const float* __restrict__ y,
                   const float* __restrict__ K,
                   int ngroups)   // total_rows / 4
{
    const int tid  = threadIdx.x;
    const int lane = tid & 63;
    const int g    = lane >> 4;          // row index within the 4-row group
    const int sl   = lane & 15;          // k-slice index
    const int k0   = sl * 16;

    // K fragment for this lane's k-slice: K[k0+i][0..2], i=0..15 (48 regs,
    // loaded once, reused for every row; 6KB matrix is L2-resident).
    float kf0[16], kf1[16], kf2[16];
#pragma unroll
    for (int i = 0; i < 16; ++i) {
        kf0[i] = K[(k0 + i) * KCOLS + 0];
        kf1[i] = K[(k0 + i) * KCOLS + 1];
        kf2[i] = K[(k0 + i) * KCOLS + 2];
    }

    const int wid    = (blockIdx.x << 2) | (tid >> 6);  // global wave id
    const int wcount = gridDim.x << 2;

    for (int grp = wid; grp < ngroups; grp += wcount) {
        const int row = (grp << 2) + g;
        const float* yr = y + (size_t)row * LATENT + k0;
        const float4 a0 = *(const float4*)(yr + 0);
        const float4 a1 = *(const float4*)(yr + 4);
        const float4 a2 = *(const float4*)(yr + 8);
        const float4 a3 = *(const float4*)(yr + 12);

        const float av[16] = { a0.x, a0.y, a0.z, a0.w,
                               a1.x, a1.y, a1.z, a1.w,
                               a2.x, a2.y, a2.z, a2.w,
                               a3.x, a3.y, a3.z, a3.w };
        float s0 = 0.f, s1 = 0.f, s2 = 0.f;
#pragma unroll
        for (int i = 0; i < 16; ++i) {   // full unroll: static indices only
            s0 += av[i] * kf0[i];
            s1 += av[i] * kf1[i];
            s2 += av[i] * kf2[i];
        }

        // Reduce across the 16 lanes of this row's group.
#pragma unroll
        for (int off = 8; off >= 1; off >>= 1) {
            s0 += __shfl_xor(s0, off, 16);
            s1 += __shfl_xor(s1, off, 16);
            s2 += __shfl_xor(s2, off, 16);
        }
        if (sl == 0) g_r[row] = make_float4(s0, s1, s2, 0.f);
    }
}

// ---------------------------------------------------------------------------
// Kernel 2 (write-bound): out[row,:] = (t(row) - t(row+1)) expanded by K^T.
// Reads r (2MB total, L2-resident) + K; pure 131MB nt-write stream.
// Block = one 32-row segment; one barrier per block; 16 blocks/CU.
// ---------------------------------------------------------------------------
__global__ __launch_bounds__(256, 8)
void pend_out_kernel(const float* __restrict__ K,
                     float* __restrict__ out)
{
    __shared__ float  sKT[3][LATENT];   // K^T, first 3 columns
    __shared__ float4 sRr[36];          // r rows [rlo..rhi] for this segment

    const int tid  = threadIdx.x;
    const int hwid = tid >> 5;          // half-wave id 0..7
    const int hl   = tid & 31;          // lane within half-wave
    const int l0   = hl * 4;

    const int chain = blockIdx.x >> 2;
    const int seg   = blockIdx.x & 3;
    const int row0  = seg * 32;
    const int rlo   = (row0 > 0) ? row0 - 1 : 0;
    const int rhi   = (row0 + 32 < NPEND) ? row0 + 32 : NPEND - 1; // inclusive
    const int nrows = rhi - rlo + 1;    // 33 or 34

    // Stage K^T (conflict-free: bank = tid%32) and the needed r rows.
    {
        const float ka = K[tid * KCOLS + 0];
        const float kb = K[tid * KCOLS + 1];
        const float kc = K[tid * KCOLS + 2];
        sKT[0][tid] = ka;
        sKT[1][tid] = kb;
        sKT[2][tid] = kc;
    }
    if (tid < nrows) sRr[tid] = g_r[chain * NPEND + rlo + tid];
    __syncthreads();

    const float4 k0a = *(const float4*)&sKT[0][l0];
    const float4 k0b = *(const float4*)&sKT[0][l0 + 128];
    const float4 k1a = *(const float4*)&sKT[1][l0];
    const float4 k1b = *(const float4*)&sKT[1][l0 + 128];
    const float4 k2a = *(const float4*)&sKT[2][l0];
    const float4 k2b = *(const float4*)&sKT[2][l0 + 128];

    const size_t cbase = (size_t)chain * ((size_t)NPEND * LATENT);

#pragma unroll
    for (int j = 0; j < 4; ++j) {
        const int i   = hwid + 8 * j;
        const int row = row0 + i;
        const int si  = row - rlo;

        const float4 rc = sRr[si];                       // broadcast read
        const float rx = rc.x, ry = rc.y, rz = rc.z;
        float px = 0.f, py = 0.f, pz = 0.f;
        if (row > 0) { const float4 rp = sRr[si - 1]; px = rp.x; py = rp.y; pz = rp.z; }

        const float dx = rx - px, dy = ry - py, dz = rz - pz;
        const float n  = sqrtf(dx*dx + dy*dy + dz*dz);
        const float s  = (n - D0_C) / n;
        float ox = s * dx, oy = s * dy, oz = s * dz;

        if (row < NPEND - 1) {
            const float4 rn = sRr[si + 1];
            const float ex = rn.x - rx, ey = rn.y - ry, ez = rn.z - rz;
            const float n2 = sqrtf(ex*ex + ey*ey + ez*ez);
            const float t2 = (n2 - D0_C) / n2;
            ox -= t2 * ex; oy -= t2 * ey; oz -= t2 * ez;
        }

        f32x4 wa, wb;
        wa.x = ox*k0a.x + oy*k1a.x + oz*k2a.x;
        wa.y = ox*k0a.y + oy*k1a.y + oz*k2a.y;
        wa.z = ox*k0a.z + oy*k1a.z + oz*k2a.z;
        wa.w = ox*k0a.w + oy*k1a.w + oz*k2a.w;
        wb.x = ox*k0b.x + oy*k1b.x + oz*k2b.x;
        wb.y = ox*k0b.y + oy*k1b.y + oz*k2b.y;
        wb.z = ox*k0b.z + oy*k1b.z + oz*k2b.z;
        wb.w = ox*k0b.w + oy*k1b.w + oz*k2b.w;

        float* orow = out + cbase + (size_t)row * LATENT;
        __builtin_nontemporal_store(wa, (f32x4*)(orow + l0));
        __builtin_nontemporal_store(wb, (f32x4*)(orow + 128 + l0));
    }
}

extern "C" void kernel_launch(void* const* d_in, const int* in_sizes, int n_in,
                              void* d_out, int out_size, void* d_ws, size_t ws_size,
                              hipStream_t stream) {
    // setup_inputs order: y[f32 N*256], z[f32 N] (unused), K[f32 256*6],
    // batch[int32 N] (unused — shape only).
    const float* y = (const float*)d_in[0];
    const float* K = (const float*)d_in[2];
    float* out = (float*)d_out;

    int N  = (n_in > 1 && in_sizes) ? in_sizes[1] : (1024 * NPEND);
    int nb = N / NPEND;
    if (nb <= 0) nb = 1024;
    if (nb > NB_MAX) nb = NB_MAX;
    N = nb * NPEND;
    (void)out_size; (void)d_ws; (void)ws_size;

    const int ngroups = N / 4;                  // 4 rows per wave-iteration
    pend_r_kernel<<<2048, 256, 0, stream>>>(y, K, ngroups);
    pend_out_kernel<<<nb * 4, 256, 0, stream>>>(K, out);
}

// Round 5
// 238.169 us; speedup vs baseline: 1.0320x; 1.0320x over previous
//
#include <hip/hip_runtime.h>

// Problem constants (fixed by the reference's setup_inputs)
#define NPEND  128
#define LATENT 256
#define KCOLS  6
#define D0_C   1.0f
#define NB_MAX 1024

typedef float f32x4 __attribute__((ext_vector_type(4)));

// Intermediate r rows (x,y,z,pad). 2 MB static device buffer (graph-safe).
static __device__ float4 g_r[(size_t)NB_MAX * NPEND];

// ---------------------------------------------------------------------------
// Kernel 1 (read-bound): r[row] = y[row,:] @ K[:,0:3].
// Pure read stream, no LDS, no barriers.
// Lane (g = lane>>4, sl = lane&15): 16-lane group g handles one row.
// Load j covers y[row][j*64 + sl*4 .. +3]: per instruction each row-group
// reads 256B contiguous -> 16 cache lines/instr (minimum; the previous
// sl*64+j*16 layout touched 64 lines/instr = 4x address-pipe amplification).
// Static 4-groups-per-wave schedule, 2-deep software pipeline with
// statically-indexed double buffers (b0,b1 reused by g2,g3) so next group's
// 4 loads are always in flight while the current group's FMA+shuffle drains.
// ---------------------------------------------------------------------------
__global__ __launch_bounds__(256, 4)
void pend_r_kernel(const float* __restrict__ y,
                   const float* __restrict__ K,
                   int ngroups)   // total_rows / 4
{
    const int tid  = threadIdx.x;
    const int lane = tid & 63;
    const int g    = lane >> 4;          // row index within the 4-row group
    const int sl   = lane & 15;          // k-chunk id

    const int nwaves = gridDim.x << 2;
    const int wid    = (blockIdx.x << 2) | (tid >> 6);

    const int g0 = wid;
    const int g1 = wid + nwaves;
    const int g2 = wid + 2 * nwaves;
    const int g3 = wid + 3 * nwaves;

    float4 b0[4], b1[4];                 // double buffer, static indices only

    auto issue = [&](int grp, float4 (&b)[4]) {
        const float* p = y + (size_t)(grp * 4 + g) * LATENT + sl * 4;
#pragma unroll
        for (int j = 0; j < 4; ++j)
            b[j] = *(const float4*)(p + j * 64);
    };

    // Issue the two lead groups' loads FIRST (HBM latency), K frags after.
    if (g0 < ngroups) issue(g0, b0);
    if (g1 < ngroups) issue(g1, b1);

    // Lane's K fragment: k(j,e) = j*64 + sl*4 + e (matches load layout).
    float kf0[16], kf1[16], kf2[16];
#pragma unroll
    for (int j = 0; j < 4; ++j)
#pragma unroll
        for (int e = 0; e < 4; ++e) {
            const int k = j * 64 + sl * 4 + e;
            kf0[4 * j + e] = K[k * KCOLS + 0];
            kf1[4 * j + e] = K[k * KCOLS + 1];
            kf2[4 * j + e] = K[k * KCOLS + 2];
        }

    auto consume = [&](const float4 (&b)[4], int grp) {
        float s0 = 0.f, s1 = 0.f, s2 = 0.f;
#pragma unroll
        for (int j = 0; j < 4; ++j) {
            const float4 a = b[j];
            s0 += a.x*kf0[4*j] + a.y*kf0[4*j+1] + a.z*kf0[4*j+2] + a.w*kf0[4*j+3];
            s1 += a.x*kf1[4*j] + a.y*kf1[4*j+1] + a.z*kf1[4*j+2] + a.w*kf1[4*j+3];
            s2 += a.x*kf2[4*j] + a.y*kf2[4*j+1] + a.z*kf2[4*j+2] + a.w*kf2[4*j+3];
        }
#pragma unroll
        for (int off = 8; off >= 1; off >>= 1) {
            s0 += __shfl_xor(s0, off, 16);
            s1 += __shfl_xor(s1, off, 16);
            s2 += __shfl_xor(s2, off, 16);
        }
        if (sl == 0) g_r[grp * 4 + g] = make_float4(s0, s1, s2, 0.f);
    };

    __builtin_amdgcn_sched_barrier(0);
    if (g0 < ngroups) consume(b0, g0);
    if (g2 < ngroups) issue(g2, b0);
    __builtin_amdgcn_sched_barrier(0);
    if (g1 < ngroups) consume(b1, g1);
    if (g3 < ngroups) issue(g3, b1);
    __builtin_amdgcn_sched_barrier(0);
    if (g2 < ngroups) consume(b0, g2);
    if (g3 < ngroups) consume(b1, g3);
}

// ---------------------------------------------------------------------------
// Kernel 2 (write-bound): out[row,:] = (t(row) - t(row+1)) expanded by K^T.
// Barrier-free persistent kernel: no LDS at all. Each lane holds its 24 K^T
// coefficients in registers (loaded once per block lifetime, amortized over
// ~8 rows/half-wave). r[row-1..row+1] are broadcast loads from g_r (uniform
// address per 32-lane half-wave -> 1 cache line each, L2-resident: 2MB).
// Pure 131MB nontemporal write stream.
// ---------------------------------------------------------------------------
__global__ __launch_bounds__(256, 4)
void pend_out_kernel(const float* __restrict__ K,
                     float* __restrict__ out,
                     int nrows)
{
    const int tid = threadIdx.x;
    const int hl  = tid & 31;           // lane within half-wave
    const int l0  = hl * 4;

    // ka[e]/ka[4+e] = K[l0+e][0], K[l0+128+e][0]; kb,kc likewise for cols 1,2.
    float ka[8], kb[8], kc[8];
#pragma unroll
    for (int e = 0; e < 4; ++e) {
        ka[e]     = K[(l0 + e) * KCOLS + 0];
        kb[e]     = K[(l0 + e) * KCOLS + 1];
        kc[e]     = K[(l0 + e) * KCOLS + 2];
        ka[4 + e] = K[(l0 + 128 + e) * KCOLS + 0];
        kb[4 + e] = K[(l0 + 128 + e) * KCOLS + 1];
        kc[4 + e] = K[(l0 + 128 + e) * KCOLS + 2];
    }

    const int hh  = blockIdx.x * 8 + (tid >> 5);   // global half-wave id
    const int nhh = gridDim.x * 8;

    for (int row = hh; row < nrows; row += nhh) {
        const int p = row & (NPEND - 1);           // index within chain

        const float4 rc = g_r[row];
        float px = 0.f, py = 0.f, pz = 0.f;
        if (p > 0) { const float4 rp = g_r[row - 1]; px = rp.x; py = rp.y; pz = rp.z; }

        const float dx = rc.x - px, dy = rc.y - py, dz = rc.z - pz;
        const float n  = sqrtf(dx*dx + dy*dy + dz*dz);
        const float s  = (n - D0_C) / n;
        float ox = s * dx, oy = s * dy, oz = s * dz;

        if (p < NPEND - 1) {
            const float4 rn = g_r[row + 1];
            const float ex = rn.x - rc.x, ey = rn.y - rc.y, ez = rn.z - rc.z;
            const float n2 = sqrtf(ex*ex + ey*ey + ez*ez);
            const float t2 = (n2 - D0_C) / n2;
            ox -= t2 * ex; oy -= t2 * ey; oz -= t2 * ez;
        }

        f32x4 wa, wb;
        wa.x = ox*ka[0] + oy*kb[0] + oz*kc[0];
        wa.y = ox*ka[1] + oy*kb[1] + oz*kc[1];
        wa.z = ox*ka[2] + oy*kb[2] + oz*kc[2];
        wa.w = ox*ka[3] + oy*kb[3] + oz*kc[3];
        wb.x = ox*ka[4] + oy*kb[4] + oz*kc[4];
        wb.y = ox*ka[5] + oy*kb[5] + oz*kc[5];
        wb.z = ox*ka[6] + oy*kb[6] + oz*kc[6];
        wb.w = ox*ka[7] + oy*kb[7] + oz*kc[7];

        float* orow = out + (size_t)row * LATENT;
        __builtin_nontemporal_store(wa, (f32x4*)(orow + l0));
        __builtin_nontemporal_store(wb, (f32x4*)(orow + 128 + l0));
    }
}

extern "C" void kernel_launch(void* const* d_in, const int* in_sizes, int n_in,
                              void* d_out, int out_size, void* d_ws, size_t ws_size,
                              hipStream_t stream) {
    // setup_inputs order: y[f32 N*256], z[f32 N] (unused), K[f32 256*6],
    // batch[int32 N] (unused — shape only).
    const float* y = (const float*)d_in[0];
    const float* K = (const float*)d_in[2];
    float* out = (float*)d_out;

    int N  = (n_in > 1 && in_sizes) ? in_sizes[1] : (1024 * NPEND);
    int nb = N / NPEND;
    if (nb <= 0) nb = 1024;
    if (nb > NB_MAX) nb = NB_MAX;
    N = nb * NPEND;
    (void)out_size; (void)d_ws; (void)ws_size;

    const int ngroups = N / 4;   // 4 rows per 16-lane group schedule
    // 2048 blocks = 8192 waves: exactly 4 groups/wave at full size (the
    // static 2-deep pipeline above covers <=4 groups/wave).
    pend_r_kernel<<<2048, 256, 0, stream>>>(y, K, ngroups);
    pend_out_kernel<<<2048, 256, 0, stream>>>(K, out, N);
}

// Round 6
// 235.917 us; speedup vs baseline: 1.0418x; 1.0095x over previous
//
#include <hip/hip_runtime.h>

// Problem constants (fixed by the reference's setup_inputs)
#define NPEND  128
#define LATENT 256
#define KCOLS  6
#define D0_C   1.0f
#define NB_MAX 1024

typedef float f32x4 __attribute__((ext_vector_type(4)));

// One block per CHAIN, two phases separated by a single barrier.
//
// Phase A (pure read stream): 16 groups of 16 lanes; group g computes
// r[g*8 .. g*8+7]. Load j of a row covers y[row][j*64 + sl*4 ..+3]: each
// instruction reads 4x256B contiguous segments (minimum line count).
// 2-deep statically-indexed double buffer: next row's 4 loads are in
// flight while the current row's 48 FMA + 4-round shuffle drain.
//
// Phase B (pure nt-write stream): 8 half-waves; half-wave hw emits rows
// hw*16 .. hw*16+15. r comes from LDS via rolling registers (1 broadcast
// ds_read per row); K^T fragment (24 regs) loaded once in the prologue.
//
// vs round 5 (split kernels, ~75us controllable): same stream purity, but
// one dispatch instead of two (one less launch gap), no g_r global round
// trip (6MB L2 traffic), and the K gathers are paid once per block
// (1024x) instead of once per wave in each kernel (8192x each).
__global__ __launch_bounds__(256, 2)
void pend_fused_kernel(const float* __restrict__ y,
                       const float* __restrict__ K,
                       float* __restrict__ out)
{
    __shared__ float4 sR[NPEND];        // r for the whole chain (2KB)

    const int tid = threadIdx.x;
    const int sl  = tid & 15;           // k-slice lane within group
    const int grp = tid >> 4;           // 0..15: rows grp*8 .. grp*8+7
    const int hl  = tid & 31;           // lane within half-wave (phase B)
    const int hw  = tid >> 5;           // 0..7: rows hw*16 .. hw*16+15
    const int l0  = hl * 4;

    const int chain = blockIdx.x;
    const float* ybase = y   + (size_t)chain * (NPEND * LATENT);
    float*       obase = out + (size_t)chain * (NPEND * LATENT);

    float4 b0[4], b1[4];                // double buffer, static indices only

    auto issueA = [&](int i, float4 (&b)[4]) {
        const float* p = ybase + (grp * 8 + i) * LATENT + sl * 4;
        b[0] = *(const float4*)(p);
        b[1] = *(const float4*)(p + 64);
        b[2] = *(const float4*)(p + 128);
        b[3] = *(const float4*)(p + 192);
    };

    // Lead loads first: row 0 hits HBM while the K gathers issue.
    issueA(0, b0);

    // Phase A K fragment: k(j,e) = j*64 + sl*4 + e  (matches load layout).
    float kf0[16], kf1[16], kf2[16];
#pragma unroll
    for (int j = 0; j < 4; ++j)
#pragma unroll
        for (int e = 0; e < 4; ++e) {
            const int k = j * 64 + sl * 4 + e;
            kf0[4 * j + e] = K[k * KCOLS + 0];
            kf1[4 * j + e] = K[k * KCOLS + 1];
            kf2[4 * j + e] = K[k * KCOLS + 2];
        }
    // Phase B K^T fragment (per half-wave lane).
    float ka[8], kb[8], kc[8];
#pragma unroll
    for (int e = 0; e < 4; ++e) {
        ka[e]     = K[(l0 + e) * KCOLS + 0];
        kb[e]     = K[(l0 + e) * KCOLS + 1];
        kc[e]     = K[(l0 + e) * KCOLS + 2];
        ka[4 + e] = K[(l0 + 128 + e) * KCOLS + 0];
        kb[4 + e] = K[(l0 + 128 + e) * KCOLS + 1];
        kc[4 + e] = K[(l0 + 128 + e) * KCOLS + 2];
    }

    auto consumeA = [&](int i, const float4 (&b)[4]) {
        float s0 = 0.f, s1 = 0.f, s2 = 0.f;
#pragma unroll
        for (int j = 0; j < 4; ++j) {
            const float4 a = b[j];
            s0 += a.x*kf0[4*j] + a.y*kf0[4*j+1] + a.z*kf0[4*j+2] + a.w*kf0[4*j+3];
            s1 += a.x*kf1[4*j] + a.y*kf1[4*j+1] + a.z*kf1[4*j+2] + a.w*kf1[4*j+3];
            s2 += a.x*kf2[4*j] + a.y*kf2[4*j+1] + a.z*kf2[4*j+2] + a.w*kf2[4*j+3];
        }
#pragma unroll
        for (int off = 8; off >= 1; off >>= 1) {
            s0 += __shfl_xor(s0, off, 16);
            s1 += __shfl_xor(s1, off, 16);
            s2 += __shfl_xor(s2, off, 16);
        }
        if (sl == 0) sR[grp * 8 + i] = make_float4(s0, s1, s2, 0.f);
    };

    // ---- Phase A: 8-row pipeline, issue(i+1) always ahead of consume(i) ----
    __builtin_amdgcn_sched_barrier(0);
    issueA(1, b1);
    __builtin_amdgcn_sched_barrier(0);
    consumeA(0, b0);
    issueA(2, b0);
    __builtin_amdgcn_sched_barrier(0);
    consumeA(1, b1);
    issueA(3, b1);
    __builtin_amdgcn_sched_barrier(0);
    consumeA(2, b0);
    issueA(4, b0);
    __builtin_amdgcn_sched_barrier(0);
    consumeA(3, b1);
    issueA(5, b1);
    __builtin_amdgcn_sched_barrier(0);
    consumeA(4, b0);
    issueA(6, b0);
    __builtin_amdgcn_sched_barrier(0);
    consumeA(5, b1);
    issueA(7, b1);
    __builtin_amdgcn_sched_barrier(0);
    consumeA(6, b0);
    consumeA(7, b1);

    __syncthreads();   // the only barrier: sR complete

    // ---- Phase B: rolling-register stencil + rank-3 expansion + nt store ----
    const int r0 = hw * 16;
    float4 rc = sR[r0];
    float4 rp = (r0 > 0) ? sR[r0 - 1] : make_float4(0.f, 0.f, 0.f, 0.f);

#pragma unroll
    for (int i = 0; i < 16; ++i) {
        const int row = r0 + i;
        const float4 rn = sR[(row < NPEND - 1) ? row + 1 : row];  // clamp

        // row==0: px..pz are the zeros staged into rp above.
        const float dx = rc.x - rp.x, dy = rc.y - rp.y, dz = rc.z - rp.z;
        const float n  = sqrtf(dx*dx + dy*dy + dz*dz);
        const float s  = (n - D0_C) / n;
        float ox = s * dx, oy = s * dy, oz = s * dz;

        if (row < NPEND - 1) {
            const float ex = rn.x - rc.x, ey = rn.y - rc.y, ez = rn.z - rc.z;
            const float n2 = sqrtf(ex*ex + ey*ey + ez*ez);
            const float t2 = (n2 - D0_C) / n2;
            ox -= t2 * ex; oy -= t2 * ey; oz -= t2 * ez;
        }

        f32x4 wa, wb;
        wa.x = ox*ka[0] + oy*kb[0] + oz*kc[0];
        wa.y = ox*ka[1] + oy*kb[1] + oz*kc[1];
        wa.z = ox*ka[2] + oy*kb[2] + oz*kc[2];
        wa.w = ox*ka[3] + oy*kb[3] + oz*kc[3];
        wb.x = ox*ka[4] + oy*kb[4] + oz*kc[4];
        wb.y = ox*ka[5] + oy*kb[5] + oz*kc[5];
        wb.z = ox*ka[6] + oy*kb[6] + oz*kc[6];
        wb.w = ox*ka[7] + oy*kb[7] + oz*kc[7];

        float* orow = obase + (size_t)row * LATENT;
        __builtin_nontemporal_store(wa, (f32x4*)(orow + l0));
        __builtin_nontemporal_store(wb, (f32x4*)(orow + 128 + l0));

        rp = rc; rc = rn;
    }
}

extern "C" void kernel_launch(void* const* d_in, const int* in_sizes, int n_in,
                              void* d_out, int out_size, void* d_ws, size_t ws_size,
                              hipStream_t stream) {
    // setup_inputs order: y[f32 N*256], z[f32 N] (unused), K[f32 256*6],
    // batch[int32 N] (unused — shape only).
    const float* y = (const float*)d_in[0];
    const float* K = (const float*)d_in[2];
    float* out = (float*)d_out;

    int N  = (n_in > 1 && in_sizes) ? in_sizes[1] : (1024 * NPEND);
    int nb = N / NPEND;
    if (nb <= 0) nb = 1024;
    if (nb > NB_MAX) nb = NB_MAX;
    (void)out_size; (void)d_ws; (void)ws_size;

    pend_fused_kernel<<<nb, 256, 0, stream>>>(y, K, out);
}